// Round 4
// baseline (871.109 us; speedup 1.0000x reference)
//
#include <hip/hip_runtime.h>
#include <hip/hip_bf16.h>
#include <math.h>

#define N_NUC_C 100000
#define N_NN_C  1600000
#define EMB_C   128
#define MSG_C   32
#define OUT_C   128
#define NB1     98   // ceil(N_NUC / 1024) for the scan

__device__ __forceinline__ float silu_f(float y) {
    return y / (1.0f + __expf(-y));
}

// ---------------------------------------------------------------------------
// Kernel A: node projections  proj[pr][n][c] = embed[n] @ W + b
// ---------------------------------------------------------------------------
__global__ __launch_bounds__(256) void proj_kernel(
    const float* __restrict__ s_embed, const float* __restrict__ r_embed,
    const float* __restrict__ W_s, const float* __restrict__ b_s,
    const float* __restrict__ W_r, const float* __restrict__ b_r,
    float* __restrict__ proj /* [2][N_NUC][MSG] */)
{
    const int n   = blockIdx.x * blockDim.x + threadIdx.x;
    const int sub = blockIdx.y;       // 0..3
    const int pr  = sub >> 1;
    const int c0  = (sub & 1) * 16;
    if (n >= N_NUC_C) return;

    const float* __restrict__ src = pr ? r_embed : s_embed;
    const float* __restrict__ W   = pr ? W_r : W_s;
    const float* __restrict__ b   = pr ? b_r : b_s;
    float* __restrict__ dst = proj + (size_t)pr * N_NUC_C * MSG_C;

    float acc[16];
    #pragma unroll
    for (int i = 0; i < 16; ++i) acc[i] = b[c0 + i];

    const float* row = src + (size_t)n * EMB_C;
    #pragma unroll 4
    for (int k = 0; k < EMB_C; k += 4) {
        const float4 rv = *reinterpret_cast<const float4*>(row + k);
        #pragma unroll
        for (int i = 0; i < 16; ++i) {
            acc[i] = fmaf(rv.x, W[(k + 0) * MSG_C + c0 + i], acc[i]);
            acc[i] = fmaf(rv.y, W[(k + 1) * MSG_C + c0 + i], acc[i]);
            acc[i] = fmaf(rv.z, W[(k + 2) * MSG_C + c0 + i], acc[i]);
            acc[i] = fmaf(rv.w, W[(k + 3) * MSG_C + c0 + i], acc[i]);
        }
    }

    float4* d = reinterpret_cast<float4*>(dst + (size_t)n * MSG_C + c0);
    d[0] = make_float4(acc[0],  acc[1],  acc[2],  acc[3]);
    d[1] = make_float4(acc[4],  acc[5],  acc[6],  acc[7]);
    d[2] = make_float4(acc[8],  acc[9],  acc[10], acc[11]);
    d[3] = make_float4(acc[12], acc[13], acc[14], acc[15]);
}

// ---------------------------------------------------------------------------
// CSR build: rank pass (1.6M int atomics)
// ---------------------------------------------------------------------------
__global__ __launch_bounds__(256) void rank_kernel(
    const int* __restrict__ receivers, int* __restrict__ cnt,
    int* __restrict__ rank)
{
    const int e = blockIdx.x * blockDim.x + threadIdx.x;
    if (e >= N_NN_C) return;
    rank[e] = atomicAdd(&cnt[receivers[e]], 1);
}

// Exclusive scan of cnt[N_NUC] -> offsets. Three tiny kernels.
__global__ __launch_bounds__(256) void scan1_kernel(
    const int* __restrict__ cnt, int* __restrict__ excl, int* __restrict__ blockTot)
{
    __shared__ int waveTot[4];
    const int t = threadIdx.x, b = blockIdx.x;
    const int lane = t & 63, wid = t >> 6;
    const int base = b * 1024 + t * 4;

    int d0 = (base + 0 < N_NUC_C) ? cnt[base + 0] : 0;
    int d1 = (base + 1 < N_NUC_C) ? cnt[base + 1] : 0;
    int d2 = (base + 2 < N_NUC_C) ? cnt[base + 2] : 0;
    int d3 = (base + 3 < N_NUC_C) ? cnt[base + 3] : 0;
    const int s = d0 + d1 + d2 + d3;

    int incl = s;
    #pragma unroll
    for (int off = 1; off < 64; off <<= 1) {
        int v = __shfl_up(incl, off);
        if (lane >= off) incl += v;
    }
    const int wexcl = incl - s;
    if (lane == 63) waveTot[wid] = incl;
    __syncthreads();
    int wbase = 0;
    for (int w = 0; w < wid; ++w) wbase += waveTot[w];
    const int e0 = wbase + wexcl;

    if (base + 0 < N_NUC_C) excl[base + 0] = e0;
    if (base + 1 < N_NUC_C) excl[base + 1] = e0 + d0;
    if (base + 2 < N_NUC_C) excl[base + 2] = e0 + d0 + d1;
    if (base + 3 < N_NUC_C) excl[base + 3] = e0 + d0 + d1 + d2;
    if (t == 255) blockTot[b] = wbase + incl;
}

__global__ __launch_bounds__(128) void scan2_kernel(
    const int* __restrict__ blockTot, int* __restrict__ blockOff)
{
    __shared__ int sh[128];
    const int t = threadIdx.x;
    const int v = (t < NB1) ? blockTot[t] : 0;
    sh[t] = v;
    __syncthreads();
    #pragma unroll
    for (int off = 1; off < 128; off <<= 1) {
        int x = 0;
        if (t >= off) x = sh[t - off];
        __syncthreads();
        sh[t] += x;
        __syncthreads();
    }
    if (t < NB1) blockOff[t] = sh[t] - v;
}

__global__ __launch_bounds__(256) void scan3_kernel(
    const int* __restrict__ excl, const int* __restrict__ blockOff,
    int* __restrict__ offsets)
{
    const int n = blockIdx.x * blockDim.x + threadIdx.x;
    if (n < N_NUC_C) offsets[n] = excl[n] + blockOff[n >> 10];
    if (n == 0) offsets[N_NUC_C] = N_NN_C;
}

// ---------------------------------------------------------------------------
// Scatter (edge id, sender) into CSR slot: one 8B random store per edge.
// ---------------------------------------------------------------------------
__global__ __launch_bounds__(256) void scatter_pack_kernel(
    const int* __restrict__ senders, const int* __restrict__ receivers,
    const int* __restrict__ rank, const int* __restrict__ offsets,
    int2* __restrict__ edge_pack)
{
    const int e = blockIdx.x * blockDim.x + threadIdx.x;
    if (e >= N_NN_C) return;
    const int dst = offsets[receivers[e]] + rank[e];
    edge_pack[dst] = make_int2(e, senders[e]);
}

// ---------------------------------------------------------------------------
// Fused gather + per-edge math + segmented reduce. 16 lanes per node
// (4 nodes/wave, 16 nodes/block, 6250 blocks). Lane sub handles CSR slots
// beg+sub, beg+sub+16, ... Accumulate in registers, butterfly over the
// 16-lane group, lane 0 stores the node row. No f32 atomics, no val array.
// ---------------------------------------------------------------------------
__global__ __launch_bounds__(256) void fused_msg_kernel(
    const float* __restrict__ proj,      // [2][N_NUC][MSG]
    const float* __restrict__ e_embed,   // [N_NN][MSG]
    const int2*  __restrict__ edge_pack, // [N_NN] (e, sender) in CSR order
    const int*   __restrict__ offsets,
    const float* __restrict__ ln_scale,
    const float* __restrict__ ln_bias,
    const float* __restrict__ W_e,       // [MSG][MSG]
    float*       __restrict__ msg)       // [N_NUC][MSG]
{
    const int tid  = threadIdx.x;
    const int lane = tid & 63;
    const int grp  = lane >> 4;                    // 0..3 within wave
    const int sub  = lane & 15;                    // 0..15 within group
    const int n    = blockIdx.x * 16 + (tid >> 6) * 4 + grp;  // < 100000 always

    const int beg = offsets[n];
    const int end = offsets[n + 1];

    const float4* pq = reinterpret_cast<const float4*>(proj + (size_t)(N_NUC_C + n) * MSG_C);

    float acc[MSG_C];
    #pragma unroll
    for (int c = 0; c < MSG_C; ++c) acc[c] = 0.0f;

    for (int slot = beg + sub; slot < end; slot += 16) {
        const int2 pk = edge_pack[slot];
        const int e = pk.x;
        const int s = pk.y;

        const float4* ee = reinterpret_cast<const float4*>(e_embed + (size_t)e * MSG_C);
        const float4* ps = reinterpret_cast<const float4*>(proj + (size_t)s * MSG_C);

        // load edge embedding, compute gate (W_e wave-uniform -> s_loads)
        float ev[MSG_C];
        #pragma unroll
        for (int q = 0; q < 8; ++q) {
            const float4 v = ee[q];
            ev[4*q+0] = v.x; ev[4*q+1] = v.y; ev[4*q+2] = v.z; ev[4*q+3] = v.w;
        }
        // x = proj_s[s] + proj_r[n]
        float x[MSG_C];
        #pragma unroll
        for (int q = 0; q < 8; ++q) {
            const float4 a = ps[q];
            const float4 b = pq[q];
            x[4*q+0] = a.x + b.x; x[4*q+1] = a.y + b.y;
            x[4*q+2] = a.z + b.z; x[4*q+3] = a.w + b.w;
        }

        float g[MSG_C];
        #pragma unroll
        for (int c = 0; c < MSG_C; ++c) g[c] = 0.0f;
        #pragma unroll
        for (int k = 0; k < MSG_C; ++k) {
            const float ek = ev[k];
            #pragma unroll
            for (int c = 0; c < MSG_C; ++c)
                g[c] = fmaf(ek, W_e[k * MSG_C + c], g[c]);
        }

        // LayerNorm + SiLU, fused accumulate
        float mu = 0.0f;
        #pragma unroll
        for (int c = 0; c < MSG_C; ++c) mu += x[c];
        mu *= (1.0f / MSG_C);
        float var = 0.0f;
        #pragma unroll
        for (int c = 0; c < MSG_C; ++c) { const float d = x[c] - mu; var = fmaf(d, d, var); }
        var *= (1.0f / MSG_C);
        const float rs = rsqrtf(var + 1e-6f);

        #pragma unroll
        for (int c = 0; c < MSG_C; ++c) {
            const float y = (x[c] - mu) * rs * ln_scale[c] + ln_bias[c];
            acc[c] = fmaf(silu_f(y), g[c], acc[c]);
        }
    }

    // 16-lane butterfly reduction of the 32-vector
    #pragma unroll
    for (int m = 8; m >= 1; m >>= 1) {
        #pragma unroll
        for (int c = 0; c < MSG_C; ++c)
            acc[c] += __shfl_xor(acc[c], m, 16);
    }

    if (sub == 0) {
        float4* d = reinterpret_cast<float4*>(msg + (size_t)n * MSG_C);
        #pragma unroll
        for (int q = 0; q < 8; ++q)
            d[q] = make_float4(acc[4*q+0], acc[4*q+1], acc[4*q+2], acc[4*q+3]);
    }
}

// ---------------------------------------------------------------------------
// Fallback (tiny ws): R1 atomic edge kernel
// ---------------------------------------------------------------------------
__global__ __launch_bounds__(256) void edge_kernel(
    const float* __restrict__ proj, const float* __restrict__ e_embed,
    const int* __restrict__ senders, const int* __restrict__ receivers,
    const float* __restrict__ ln_scale, const float* __restrict__ ln_bias,
    const float* __restrict__ W_e, float* __restrict__ msg)
{
    const int e = blockIdx.x * blockDim.x + threadIdx.x;
    if (e >= N_NN_C) return;
    const int s = senders[e];
    const int r = receivers[e];
    const float4* ps = reinterpret_cast<const float4*>(proj + (size_t)s * MSG_C);
    const float4* pq = reinterpret_cast<const float4*>(proj + (size_t)(N_NUC_C + r) * MSG_C);
    float x[MSG_C];
    #pragma unroll
    for (int q = 0; q < 8; ++q) {
        const float4 a = ps[q];
        const float4 b = pq[q];
        x[4*q+0] = a.x + b.x; x[4*q+1] = a.y + b.y;
        x[4*q+2] = a.z + b.z; x[4*q+3] = a.w + b.w;
    }
    float mu = 0.0f;
    #pragma unroll
    for (int c = 0; c < MSG_C; ++c) mu += x[c];
    mu *= (1.0f / MSG_C);
    float var = 0.0f;
    #pragma unroll
    for (int c = 0; c < MSG_C; ++c) { const float d = x[c] - mu; var = fmaf(d, d, var); }
    var *= (1.0f / MSG_C);
    const float rs = rsqrtf(var + 1e-6f);
    #pragma unroll
    for (int c = 0; c < MSG_C; ++c) {
        const float y = (x[c] - mu) * rs * ln_scale[c] + ln_bias[c];
        x[c] = silu_f(y);
    }
    float ev[MSG_C];
    const float4* ee = reinterpret_cast<const float4*>(e_embed + (size_t)e * MSG_C);
    #pragma unroll
    for (int q = 0; q < 8; ++q) {
        const float4 v = ee[q];
        ev[4*q+0] = v.x; ev[4*q+1] = v.y; ev[4*q+2] = v.z; ev[4*q+3] = v.w;
    }
    float g[MSG_C];
    #pragma unroll
    for (int c = 0; c < MSG_C; ++c) g[c] = 0.0f;
    #pragma unroll
    for (int k = 0; k < MSG_C; ++k) {
        const float ek = ev[k];
        #pragma unroll
        for (int c = 0; c < MSG_C; ++c) g[c] = fmaf(ek, W_e[k * MSG_C + c], g[c]);
    }
    float* mrow = msg + (size_t)r * MSG_C;
    #pragma unroll
    for (int c = 0; c < MSG_C; ++c) atomicAdd(mrow + c, x[c] * g[c]);
}

// ---------------------------------------------------------------------------
// Kernel C: out[n][j] = silu( (msg[n] . W_out[:,j]) * norm[n] )
// ---------------------------------------------------------------------------
__global__ __launch_bounds__(256) void out_kernel(
    const float* __restrict__ msg, const float* __restrict__ norm,
    const float* __restrict__ W_out, float* __restrict__ out)
{
    const int j     = threadIdx.x & (OUT_C - 1);
    const int local = threadIdx.x >> 7;

    float w[MSG_C];
    #pragma unroll
    for (int k = 0; k < MSG_C; ++k) w[k] = W_out[k * OUT_C + j];

    for (int n = blockIdx.x * 2 + local; n < N_NUC_C; n += gridDim.x * 2) {
        const float4* m4 = reinterpret_cast<const float4*>(msg + (size_t)n * MSG_C);
        float acc = 0.0f;
        #pragma unroll
        for (int q = 0; q < 8; ++q) {
            const float4 mv = m4[q];
            acc = fmaf(mv.x, w[4*q+0], acc);
            acc = fmaf(mv.y, w[4*q+1], acc);
            acc = fmaf(mv.z, w[4*q+2], acc);
            acc = fmaf(mv.w, w[4*q+3], acc);
        }
        acc *= norm[n];
        out[(size_t)n * OUT_C + j] = silu_f(acc);
    }
}

extern "C" void kernel_launch(void* const* d_in, const int* in_sizes, int n_in,
                              void* d_out, int out_size, void* d_ws, size_t ws_size,
                              hipStream_t stream) {
    const float* s_embed   = (const float*)d_in[0];
    const float* r_embed   = (const float*)d_in[1];
    const float* e_embed   = (const float*)d_in[2];
    const float* norm      = (const float*)d_in[3];
    const int*   senders   = (const int*)d_in[4];
    const int*   receivers = (const int*)d_in[5];
    const float* W_s       = (const float*)d_in[6];
    const float* b_s       = (const float*)d_in[7];
    const float* W_r       = (const float*)d_in[8];
    const float* b_r       = (const float*)d_in[9];
    const float* ln_scale  = (const float*)d_in[10];
    const float* ln_bias   = (const float*)d_in[11];
    const float* W_e       = (const float*)d_in[12];
    const float* W_out     = (const float*)d_in[13];
    float* out = (float*)d_out;

    char* ws = (char*)d_ws;
    size_t off = 0;
    auto alloc = [&](size_t bytes) { char* p = ws + off; off += (bytes + 255) & ~(size_t)255; return p; };

    float* proj      = (float*)alloc((size_t)2 * N_NUC_C * MSG_C * 4); // 25.6 MB
    float* msg       = (float*)alloc((size_t)N_NUC_C * MSG_C * 4);     // 12.8 MB
    const size_t off_min = off;                                        // 38.4 MB
    int*   cnt       = (int*)  alloc((size_t)N_NUC_C * 4);
    int*   excl      = (int*)  alloc((size_t)N_NUC_C * 4);
    int*   offsets   = (int*)  alloc((size_t)(N_NUC_C + 1) * 4);
    int*   blockTot  = (int*)  alloc(128 * 4);
    int*   blockOff  = (int*)  alloc(128 * 4);
    int*   rank      = (int*)  alloc((size_t)N_NN_C * 4);              // 6.4 MB
    int2*  edge_pack = (int2*) alloc((size_t)N_NN_C * 8);              // 12.8 MB
    const size_t off_full = off;                                       // ~59 MB

    dim3 pgrid((N_NUC_C + 255) / 256, 4);
    proj_kernel<<<pgrid, 256, 0, stream>>>(s_embed, r_embed, W_s, b_s, W_r, b_r, proj);

    if (off_full <= ws_size) {
        // --- CSR + fused gather/reduce (no f32 atomics, no val round-trip) ---
        hipMemsetAsync(cnt, 0, (size_t)N_NUC_C * 4, stream);
        rank_kernel<<<(N_NN_C + 255) / 256, 256, 0, stream>>>(receivers, cnt, rank);
        scan1_kernel<<<NB1, 256, 0, stream>>>(cnt, excl, blockTot);
        scan2_kernel<<<1, 128, 0, stream>>>(blockTot, blockOff);
        scan3_kernel<<<(N_NUC_C + 255) / 256, 256, 0, stream>>>(excl, blockOff, offsets);
        scatter_pack_kernel<<<(N_NN_C + 255) / 256, 256, 0, stream>>>(
            senders, receivers, rank, offsets, edge_pack);
        fused_msg_kernel<<<N_NUC_C / 16, 256, 0, stream>>>(
            proj, e_embed, edge_pack, offsets, ln_scale, ln_bias, W_e, msg);
    } else if (off_min <= ws_size) {
        // --- fallback: R1 atomic path ---
        hipMemsetAsync(msg, 0, (size_t)N_NUC_C * MSG_C * 4, stream);
        edge_kernel<<<(N_NN_C + 255) / 256, 256, 0, stream>>>(
            proj, e_embed, senders, receivers, ln_scale, ln_bias, W_e, msg);
    }

    out_kernel<<<2048, 256, 0, stream>>>(msg, norm, W_out, out);
}

// Round 5
// 444.932 us; speedup vs baseline: 1.9578x; 1.9578x over previous
//
#include <hip/hip_runtime.h>
#include <hip/hip_bf16.h>
#include <math.h>

#define N_NUC_C 100000
#define N_NN_C  1600000
#define EMB_C   128
#define MSG_C   32
#define OUT_C   128
#define NB1     98   // ceil(N_NUC / 1024) for the scan
#define LDS_STR 33   // padded LDS row stride (floats)

__device__ __forceinline__ float silu_f(float y) {
    return y / (1.0f + __expf(-y));
}

// ---------------------------------------------------------------------------
// Kernel A: node projections  proj[pr][n][c] = embed[n] @ W + b
// ---------------------------------------------------------------------------
__global__ __launch_bounds__(256) void proj_kernel(
    const float* __restrict__ s_embed, const float* __restrict__ r_embed,
    const float* __restrict__ W_s, const float* __restrict__ b_s,
    const float* __restrict__ W_r, const float* __restrict__ b_r,
    float* __restrict__ proj /* [2][N_NUC][MSG] */)
{
    const int n   = blockIdx.x * blockDim.x + threadIdx.x;
    const int sub = blockIdx.y;       // 0..3
    const int pr  = sub >> 1;
    const int c0  = (sub & 1) * 16;
    if (n >= N_NUC_C) return;

    const float* __restrict__ src = pr ? r_embed : s_embed;
    const float* __restrict__ W   = pr ? W_r : W_s;
    const float* __restrict__ b   = pr ? b_r : b_s;
    float* __restrict__ dst = proj + (size_t)pr * N_NUC_C * MSG_C;

    float acc[16];
    #pragma unroll
    for (int i = 0; i < 16; ++i) acc[i] = b[c0 + i];

    const float* row = src + (size_t)n * EMB_C;
    #pragma unroll 4
    for (int k = 0; k < EMB_C; k += 4) {
        const float4 rv = *reinterpret_cast<const float4*>(row + k);
        #pragma unroll
        for (int i = 0; i < 16; ++i) {
            acc[i] = fmaf(rv.x, W[(k + 0) * MSG_C + c0 + i], acc[i]);
            acc[i] = fmaf(rv.y, W[(k + 1) * MSG_C + c0 + i], acc[i]);
            acc[i] = fmaf(rv.z, W[(k + 2) * MSG_C + c0 + i], acc[i]);
            acc[i] = fmaf(rv.w, W[(k + 3) * MSG_C + c0 + i], acc[i]);
        }
    }

    float4* d = reinterpret_cast<float4*>(dst + (size_t)n * MSG_C + c0);
    d[0] = make_float4(acc[0],  acc[1],  acc[2],  acc[3]);
    d[1] = make_float4(acc[4],  acc[5],  acc[6],  acc[7]);
    d[2] = make_float4(acc[8],  acc[9],  acc[10], acc[11]);
    d[3] = make_float4(acc[12], acc[13], acc[14], acc[15]);
}

// ---------------------------------------------------------------------------
// CSR build: count pass (1.6M int atomics, no rank array)
// ---------------------------------------------------------------------------
__global__ __launch_bounds__(256) void count_kernel(
    const int* __restrict__ receivers, int* __restrict__ cnt)
{
    const int e = blockIdx.x * blockDim.x + threadIdx.x;
    if (e >= N_NN_C) return;
    atomicAdd(&cnt[receivers[e]], 1);
}

// Exclusive scan of cnt[N_NUC] -> offsets (+ cursor copy). Three tiny kernels.
__global__ __launch_bounds__(256) void scan1_kernel(
    const int* __restrict__ cnt, int* __restrict__ excl, int* __restrict__ blockTot)
{
    __shared__ int waveTot[4];
    const int t = threadIdx.x, b = blockIdx.x;
    const int lane = t & 63, wid = t >> 6;
    const int base = b * 1024 + t * 4;

    int d0 = (base + 0 < N_NUC_C) ? cnt[base + 0] : 0;
    int d1 = (base + 1 < N_NUC_C) ? cnt[base + 1] : 0;
    int d2 = (base + 2 < N_NUC_C) ? cnt[base + 2] : 0;
    int d3 = (base + 3 < N_NUC_C) ? cnt[base + 3] : 0;
    const int s = d0 + d1 + d2 + d3;

    int incl = s;
    #pragma unroll
    for (int off = 1; off < 64; off <<= 1) {
        int v = __shfl_up(incl, off);
        if (lane >= off) incl += v;
    }
    const int wexcl = incl - s;
    if (lane == 63) waveTot[wid] = incl;
    __syncthreads();
    int wbase = 0;
    for (int w = 0; w < wid; ++w) wbase += waveTot[w];
    const int e0 = wbase + wexcl;

    if (base + 0 < N_NUC_C) excl[base + 0] = e0;
    if (base + 1 < N_NUC_C) excl[base + 1] = e0 + d0;
    if (base + 2 < N_NUC_C) excl[base + 2] = e0 + d0 + d1;
    if (base + 3 < N_NUC_C) excl[base + 3] = e0 + d0 + d1 + d2;
    if (t == 255) blockTot[b] = wbase + incl;
}

__global__ __launch_bounds__(128) void scan2_kernel(
    const int* __restrict__ blockTot, int* __restrict__ blockOff)
{
    __shared__ int sh[128];
    const int t = threadIdx.x;
    const int v = (t < NB1) ? blockTot[t] : 0;
    sh[t] = v;
    __syncthreads();
    #pragma unroll
    for (int off = 1; off < 128; off <<= 1) {
        int x = 0;
        if (t >= off) x = sh[t - off];
        __syncthreads();
        sh[t] += x;
        __syncthreads();
    }
    if (t < NB1) blockOff[t] = sh[t] - v;
}

__global__ __launch_bounds__(256) void scan3_kernel(
    const int* __restrict__ excl, const int* __restrict__ blockOff,
    int* __restrict__ offsets, int* __restrict__ cursor)
{
    const int n = blockIdx.x * blockDim.x + threadIdx.x;
    if (n < N_NUC_C) {
        const int v = excl[n] + blockOff[n >> 10];
        offsets[n] = v;
        cursor[n]  = v;
    }
    if (n == 0) offsets[N_NUC_C] = N_NN_C;
}

// ---------------------------------------------------------------------------
// Scatter (edge, sender, receiver) into CSR slot via cursor atomics.
// ---------------------------------------------------------------------------
__global__ __launch_bounds__(256) void scatter_pack_kernel(
    const int* __restrict__ senders, const int* __restrict__ receivers,
    int* __restrict__ cursor, int4* __restrict__ edge_pack)
{
    const int e = blockIdx.x * blockDim.x + threadIdx.x;
    if (e >= N_NN_C) return;
    const int r = receivers[e];
    const int dst = atomicAdd(&cursor[r], 1);
    edge_pack[dst] = make_int4(e, senders[e], r, 0);
}

// ---------------------------------------------------------------------------
// Fused CSR edge compute + in-block segmented reduction.
// Block = 256 consecutive CSR slots. Thread = one slot, single-shot math
// (no cross-loop register state). Message -> LDS (stride 33, conflict-free).
// Then (receiver, channel) threads sum contiguous LDS slots; interior
// segments plain-store, straddling segments atomicAdd (~2 per block).
// ---------------------------------------------------------------------------
__global__ __launch_bounds__(256) void fused_csr_kernel(
    const float* __restrict__ proj,      // [2][N_NUC][MSG]
    const float* __restrict__ e_embed,   // [N_NN][MSG]
    const int4*  __restrict__ edge_pack, // [N_NN] (e, s, r, 0) CSR order
    const int*   __restrict__ offsets,   // [N_NUC+1]
    const float* __restrict__ ln_scale,
    const float* __restrict__ ln_bias,
    const float* __restrict__ W_e,       // [MSG][MSG]
    float*       __restrict__ msg)       // [N_NUC][MSG], pre-zeroed
{
    __shared__ float lds_o[256 * LDS_STR];
    __shared__ int   lds_r[256];

    const int t  = threadIdx.x;
    const int B0 = blockIdx.x * 256;     // first slot of this block

    // ---- phase 1: per-edge message (single-shot, straight-line) ----
    const int4 pk = edge_pack[B0 + t];
    const int e = pk.x, s = pk.y, r = pk.z;
    lds_r[t] = r;

    const float4* ee = reinterpret_cast<const float4*>(e_embed + (size_t)e * MSG_C);
    const float4* ps = reinterpret_cast<const float4*>(proj + (size_t)s * MSG_C);
    const float4* pq = reinterpret_cast<const float4*>(proj + (size_t)(N_NUC_C + r) * MSG_C);

    float ev[MSG_C], x[MSG_C];
    #pragma unroll
    for (int q = 0; q < 8; ++q) {
        const float4 v = ee[q];
        ev[4*q+0] = v.x; ev[4*q+1] = v.y; ev[4*q+2] = v.z; ev[4*q+3] = v.w;
    }
    #pragma unroll
    for (int q = 0; q < 8; ++q) {
        const float4 a = ps[q];
        const float4 b = pq[q];
        x[4*q+0] = a.x + b.x; x[4*q+1] = a.y + b.y;
        x[4*q+2] = a.z + b.z; x[4*q+3] = a.w + b.w;
    }

    // gate = e_embed[e] @ W_e (wave-uniform W_e -> scalar operands)
    float g[MSG_C];
    #pragma unroll
    for (int c = 0; c < MSG_C; ++c) g[c] = 0.0f;
    #pragma unroll
    for (int k = 0; k < MSG_C; ++k) {
        const float ek = ev[k];
        #pragma unroll
        for (int c = 0; c < MSG_C; ++c)
            g[c] = fmaf(ek, W_e[k * MSG_C + c], g[c]);
    }

    // LayerNorm + SiLU, write message straight to LDS
    float mu = 0.0f;
    #pragma unroll
    for (int c = 0; c < MSG_C; ++c) mu += x[c];
    mu *= (1.0f / MSG_C);
    float var = 0.0f;
    #pragma unroll
    for (int c = 0; c < MSG_C; ++c) { const float d = x[c] - mu; var = fmaf(d, d, var); }
    var *= (1.0f / MSG_C);
    const float rs = rsqrtf(var + 1e-6f);

    float* orow = &lds_o[t * LDS_STR];
    #pragma unroll
    for (int c = 0; c < MSG_C; ++c) {
        const float y = (x[c] - mu) * rs * ln_scale[c] + ln_bias[c];
        orow[c] = silu_f(y) * g[c];
    }

    __syncthreads();

    // ---- phase 2: segmented reduction over receivers in this block ----
    const int r0 = lds_r[0];
    const int r1 = lds_r[255];
    const int total = (r1 - r0 + 1) << 5;   // (#receivers) * 32 channels

    for (int p = t; p < total; p += 256) {
        const int n  = r0 + (p >> 5);
        const int ch = p & 31;
        int b  = offsets[n];
        int en = offsets[n + 1];
        const bool interior = (b >= B0) && (en <= B0 + 256);
        if (b < B0) b = B0;
        if (en > B0 + 256) en = B0 + 256;

        float sum = 0.0f;
        for (int q = b - B0; q < en - B0; ++q)
            sum += lds_o[q * LDS_STR + ch];

        float* dst = msg + (size_t)n * MSG_C + ch;
        if (interior)       *dst = sum;          // sole owner (incl. empty = 0)
        else if (en > b)    atomicAdd(dst, sum); // straddling segment part
    }
}

// ---------------------------------------------------------------------------
// Fallback (tiny ws): R1 atomic edge kernel
// ---------------------------------------------------------------------------
__global__ __launch_bounds__(256) void edge_kernel(
    const float* __restrict__ proj, const float* __restrict__ e_embed,
    const int* __restrict__ senders, const int* __restrict__ receivers,
    const float* __restrict__ ln_scale, const float* __restrict__ ln_bias,
    const float* __restrict__ W_e, float* __restrict__ msg)
{
    const int e = blockIdx.x * blockDim.x + threadIdx.x;
    if (e >= N_NN_C) return;
    const int s = senders[e];
    const int r = receivers[e];
    const float4* ps = reinterpret_cast<const float4*>(proj + (size_t)s * MSG_C);
    const float4* pq = reinterpret_cast<const float4*>(proj + (size_t)(N_NUC_C + r) * MSG_C);
    float x[MSG_C];
    #pragma unroll
    for (int q = 0; q < 8; ++q) {
        const float4 a = ps[q];
        const float4 b = pq[q];
        x[4*q+0] = a.x + b.x; x[4*q+1] = a.y + b.y;
        x[4*q+2] = a.z + b.z; x[4*q+3] = a.w + b.w;
    }
    float mu = 0.0f;
    #pragma unroll
    for (int c = 0; c < MSG_C; ++c) mu += x[c];
    mu *= (1.0f / MSG_C);
    float var = 0.0f;
    #pragma unroll
    for (int c = 0; c < MSG_C; ++c) { const float d = x[c] - mu; var = fmaf(d, d, var); }
    var *= (1.0f / MSG_C);
    const float rs = rsqrtf(var + 1e-6f);
    #pragma unroll
    for (int c = 0; c < MSG_C; ++c) {
        const float y = (x[c] - mu) * rs * ln_scale[c] + ln_bias[c];
        x[c] = silu_f(y);
    }
    float ev[MSG_C];
    const float4* ee = reinterpret_cast<const float4*>(e_embed + (size_t)e * MSG_C);
    #pragma unroll
    for (int q = 0; q < 8; ++q) {
        const float4 v = ee[q];
        ev[4*q+0] = v.x; ev[4*q+1] = v.y; ev[4*q+2] = v.z; ev[4*q+3] = v.w;
    }
    float g[MSG_C];
    #pragma unroll
    for (int c = 0; c < MSG_C; ++c) g[c] = 0.0f;
    #pragma unroll
    for (int k = 0; k < MSG_C; ++k) {
        const float ek = ev[k];
        #pragma unroll
        for (int c = 0; c < MSG_C; ++c) g[c] = fmaf(ek, W_e[k * MSG_C + c], g[c]);
    }
    float* mrow = msg + (size_t)r * MSG_C;
    #pragma unroll
    for (int c = 0; c < MSG_C; ++c) atomicAdd(mrow + c, x[c] * g[c]);
}

// ---------------------------------------------------------------------------
// Kernel C: out[n][j] = silu( (msg[n] . W_out[:,j]) * norm[n] )
// ---------------------------------------------------------------------------
__global__ __launch_bounds__(256) void out_kernel(
    const float* __restrict__ msg, const float* __restrict__ norm,
    const float* __restrict__ W_out, float* __restrict__ out)
{
    const int j     = threadIdx.x & (OUT_C - 1);
    const int local = threadIdx.x >> 7;

    float w[MSG_C];
    #pragma unroll
    for (int k = 0; k < MSG_C; ++k) w[k] = W_out[k * OUT_C + j];

    for (int n = blockIdx.x * 2 + local; n < N_NUC_C; n += gridDim.x * 2) {
        const float4* m4 = reinterpret_cast<const float4*>(msg + (size_t)n * MSG_C);
        float acc = 0.0f;
        #pragma unroll
        for (int q = 0; q < 8; ++q) {
            const float4 mv = m4[q];
            acc = fmaf(mv.x, w[4*q+0], acc);
            acc = fmaf(mv.y, w[4*q+1], acc);
            acc = fmaf(mv.z, w[4*q+2], acc);
            acc = fmaf(mv.w, w[4*q+3], acc);
        }
        acc *= norm[n];
        out[(size_t)n * OUT_C + j] = silu_f(acc);
    }
}

extern "C" void kernel_launch(void* const* d_in, const int* in_sizes, int n_in,
                              void* d_out, int out_size, void* d_ws, size_t ws_size,
                              hipStream_t stream) {
    const float* s_embed   = (const float*)d_in[0];
    const float* r_embed   = (const float*)d_in[1];
    const float* e_embed   = (const float*)d_in[2];
    const float* norm      = (const float*)d_in[3];
    const int*   senders   = (const int*)d_in[4];
    const int*   receivers = (const int*)d_in[5];
    const float* W_s       = (const float*)d_in[6];
    const float* b_s       = (const float*)d_in[7];
    const float* W_r       = (const float*)d_in[8];
    const float* b_r       = (const float*)d_in[9];
    const float* ln_scale  = (const float*)d_in[10];
    const float* ln_bias   = (const float*)d_in[11];
    const float* W_e       = (const float*)d_in[12];
    const float* W_out     = (const float*)d_in[13];
    float* out = (float*)d_out;

    char* ws = (char*)d_ws;
    size_t off = 0;
    auto alloc = [&](size_t bytes) { char* p = ws + off; off += (bytes + 255) & ~(size_t)255; return p; };

    float* proj      = (float*)alloc((size_t)2 * N_NUC_C * MSG_C * 4); // 25.6 MB
    float* msg       = (float*)alloc((size_t)N_NUC_C * MSG_C * 4);     // 12.8 MB
    const size_t off_min = off;                                        // 38.4 MB
    int*   cnt       = (int*)  alloc((size_t)N_NUC_C * 4);
    int*   excl      = (int*)  alloc((size_t)N_NUC_C * 4);
    int*   offsets   = (int*)  alloc((size_t)(N_NUC_C + 1) * 4);
    int*   cursor    = (int*)  alloc((size_t)N_NUC_C * 4);
    int*   blockTot  = (int*)  alloc(128 * 4);
    int*   blockOff  = (int*)  alloc(128 * 4);
    int4*  edge_pack = (int4*) alloc((size_t)N_NN_C * 16);             // 25.6 MB
    const size_t off_full = off;                                       // ~65.7 MB

    dim3 pgrid((N_NUC_C + 255) / 256, 4);
    proj_kernel<<<pgrid, 256, 0, stream>>>(s_embed, r_embed, W_s, b_s, W_r, b_r, proj);

    if (off_full <= ws_size) {
        // --- CSR + fused edge-compute/in-block-reduce ---
        hipMemsetAsync(cnt, 0, (size_t)N_NUC_C * 4, stream);
        hipMemsetAsync(msg, 0, (size_t)N_NUC_C * MSG_C * 4, stream);
        count_kernel<<<(N_NN_C + 255) / 256, 256, 0, stream>>>(receivers, cnt);
        scan1_kernel<<<NB1, 256, 0, stream>>>(cnt, excl, blockTot);
        scan2_kernel<<<1, 128, 0, stream>>>(blockTot, blockOff);
        scan3_kernel<<<(N_NUC_C + 255) / 256, 256, 0, stream>>>(excl, blockOff, offsets, cursor);
        scatter_pack_kernel<<<(N_NN_C + 255) / 256, 256, 0, stream>>>(
            senders, receivers, cursor, edge_pack);
        fused_csr_kernel<<<N_NN_C / 256, 256, 0, stream>>>(
            proj, e_embed, edge_pack, offsets, ln_scale, ln_bias, W_e, msg);
    } else if (off_min <= ws_size) {
        // --- fallback: R1 atomic path ---
        hipMemsetAsync(msg, 0, (size_t)N_NUC_C * MSG_C * 4, stream);
        edge_kernel<<<(N_NN_C + 255) / 256, 256, 0, stream>>>(
            proj, e_embed, senders, receivers, ln_scale, ln_bias, W_e, msg);
    }

    out_kernel<<<2048, 256, 0, stream>>>(msg, norm, W_out, out);
}

// Round 6
// 375.136 us; speedup vs baseline: 2.3221x; 1.1861x over previous
//
#include <hip/hip_runtime.h>
#include <hip/hip_bf16.h>
#include <math.h>

#define N_NUC_C 100000
#define N_NN_C  1600000
#define EMB_C   128
#define MSG_C   32
#define OUT_C   128
#define NB1     98   // ceil(N_NUC / 1024) for the scan
#define LDS_STR 33   // padded LDS row stride (floats)
#define NPART   8
#define R_PER_P (N_NUC_C / NPART)          // 12500 receivers per partition
#define SBLK    784                        // blocks per partition in scatter
#define STHREADS (SBLK * 256)              // 200704 threads per partition

__device__ __forceinline__ float silu_f(float y) {
    return y / (1.0f + __expf(-y));
}

// ---------------------------------------------------------------------------
// Kernel A: node projections  proj[pr][n][c] = embed[n] @ W + b
// ---------------------------------------------------------------------------
__global__ __launch_bounds__(256) void proj_kernel(
    const float* __restrict__ s_embed, const float* __restrict__ r_embed,
    const float* __restrict__ W_s, const float* __restrict__ b_s,
    const float* __restrict__ W_r, const float* __restrict__ b_r,
    float* __restrict__ proj /* [2][N_NUC][MSG] */)
{
    const int n   = blockIdx.x * blockDim.x + threadIdx.x;
    const int sub = blockIdx.y;       // 0..3
    const int pr  = sub >> 1;
    const int c0  = (sub & 1) * 16;
    if (n >= N_NUC_C) return;

    const float* __restrict__ src = pr ? r_embed : s_embed;
    const float* __restrict__ W   = pr ? W_r : W_s;
    const float* __restrict__ b   = pr ? b_r : b_s;
    float* __restrict__ dst = proj + (size_t)pr * N_NUC_C * MSG_C;

    float acc[16];
    #pragma unroll
    for (int i = 0; i < 16; ++i) acc[i] = b[c0 + i];

    const float* row = src + (size_t)n * EMB_C;
    #pragma unroll 4
    for (int k = 0; k < EMB_C; k += 4) {
        const float4 rv = *reinterpret_cast<const float4*>(row + k);
        #pragma unroll
        for (int i = 0; i < 16; ++i) {
            acc[i] = fmaf(rv.x, W[(k + 0) * MSG_C + c0 + i], acc[i]);
            acc[i] = fmaf(rv.y, W[(k + 1) * MSG_C + c0 + i], acc[i]);
            acc[i] = fmaf(rv.z, W[(k + 2) * MSG_C + c0 + i], acc[i]);
            acc[i] = fmaf(rv.w, W[(k + 3) * MSG_C + c0 + i], acc[i]);
        }
    }

    float4* d = reinterpret_cast<float4*>(dst + (size_t)n * MSG_C + c0);
    d[0] = make_float4(acc[0],  acc[1],  acc[2],  acc[3]);
    d[1] = make_float4(acc[4],  acc[5],  acc[6],  acc[7]);
    d[2] = make_float4(acc[8],  acc[9],  acc[10], acc[11]);
    d[3] = make_float4(acc[12], acc[13], acc[14], acc[15]);
}

// ---------------------------------------------------------------------------
// CSR build: count pass (1.6M int atomics)
// ---------------------------------------------------------------------------
__global__ __launch_bounds__(256) void count_kernel(
    const int* __restrict__ receivers, int* __restrict__ cnt)
{
    const int e = blockIdx.x * blockDim.x + threadIdx.x;
    if (e >= N_NN_C) return;
    atomicAdd(&cnt[receivers[e]], 1);
}

// Exclusive scan of cnt[N_NUC] -> offsets (+ cursor copy). Three tiny kernels.
__global__ __launch_bounds__(256) void scan1_kernel(
    const int* __restrict__ cnt, int* __restrict__ excl, int* __restrict__ blockTot)
{
    __shared__ int waveTot[4];
    const int t = threadIdx.x, b = blockIdx.x;
    const int lane = t & 63, wid = t >> 6;
    const int base = b * 1024 + t * 4;

    int d0 = (base + 0 < N_NUC_C) ? cnt[base + 0] : 0;
    int d1 = (base + 1 < N_NUC_C) ? cnt[base + 1] : 0;
    int d2 = (base + 2 < N_NUC_C) ? cnt[base + 2] : 0;
    int d3 = (base + 3 < N_NUC_C) ? cnt[base + 3] : 0;
    const int s = d0 + d1 + d2 + d3;

    int incl = s;
    #pragma unroll
    for (int off = 1; off < 64; off <<= 1) {
        int v = __shfl_up(incl, off);
        if (lane >= off) incl += v;
    }
    const int wexcl = incl - s;
    if (lane == 63) waveTot[wid] = incl;
    __syncthreads();
    int wbase = 0;
    for (int w = 0; w < wid; ++w) wbase += waveTot[w];
    const int e0 = wbase + wexcl;

    if (base + 0 < N_NUC_C) excl[base + 0] = e0;
    if (base + 1 < N_NUC_C) excl[base + 1] = e0 + d0;
    if (base + 2 < N_NUC_C) excl[base + 2] = e0 + d0 + d1;
    if (base + 3 < N_NUC_C) excl[base + 3] = e0 + d0 + d1 + d2;
    if (t == 255) blockTot[b] = wbase + incl;
}

__global__ __launch_bounds__(128) void scan2_kernel(
    const int* __restrict__ blockTot, int* __restrict__ blockOff)
{
    __shared__ int sh[128];
    const int t = threadIdx.x;
    const int v = (t < NB1) ? blockTot[t] : 0;
    sh[t] = v;
    __syncthreads();
    #pragma unroll
    for (int off = 1; off < 128; off <<= 1) {
        int x = 0;
        if (t >= off) x = sh[t - off];
        __syncthreads();
        sh[t] += x;
        __syncthreads();
    }
    if (t < NB1) blockOff[t] = sh[t] - v;
}

__global__ __launch_bounds__(256) void scan3_kernel(
    const int* __restrict__ excl, const int* __restrict__ blockOff,
    int* __restrict__ offsets, int* __restrict__ cursor)
{
    const int n = blockIdx.x * blockDim.x + threadIdx.x;
    if (n < N_NUC_C) {
        const int v = excl[n] + blockOff[n >> 10];
        offsets[n] = v;
        cursor[n]  = v;
    }
    if (n == 0) offsets[N_NUC_C] = N_NN_C;
}

// ---------------------------------------------------------------------------
// Partition-local scatter: 8 receiver ranges; blocks with blockIdx%8==p scan
// ALL edges (coalesced) and scatter only those with r in range p. Each pack
// line is then written by one partition's clustered blocks (one XCD under
// de-facto %8 dispatch) -> L2 write coalescing, no line bouncing. Correct
// for ANY block->XCD mapping (filter is by receiver range).
// ---------------------------------------------------------------------------
__global__ __launch_bounds__(256) void scatter_pack8_kernel(
    const int* __restrict__ senders, const int* __restrict__ receivers,
    int* __restrict__ cursor, int4* __restrict__ edge_pack)
{
    const int p    = blockIdx.x & 7;
    const int blk  = blockIdx.x >> 3;                 // 0..SBLK-1
    const int base = blk * 256 + threadIdx.x;         // 0..STHREADS-1
    const int rlo  = p * R_PER_P;
    const int rhi  = rlo + R_PER_P;

    #pragma unroll
    for (int k = 0; k < 8; ++k) {
        const int e = base + k * STHREADS;
        if (e < N_NN_C) {
            const int r = receivers[e];
            if (r >= rlo && r < rhi) {
                const int dst = atomicAdd(&cursor[r], 1);
                edge_pack[dst] = make_int4(e, senders[e], r, 0);
            }
        }
    }
}

// ---------------------------------------------------------------------------
// Fused CSR edge compute + in-block segmented reduction.
// Block = 256 consecutive CSR slots. Thread = one slot, single-shot math.
// Message -> LDS (stride 33). Then (receiver, channel) threads sum
// contiguous LDS slots; interior segments plain-store, straddling atomicAdd.
// ---------------------------------------------------------------------------
__global__ __launch_bounds__(256) void fused_csr_kernel(
    const float* __restrict__ proj,      // [2][N_NUC][MSG]
    const float* __restrict__ e_embed,   // [N_NN][MSG]
    const int4*  __restrict__ edge_pack, // [N_NN] (e, s, r, 0) CSR order
    const int*   __restrict__ offsets,   // [N_NUC+1]
    const float* __restrict__ ln_scale,
    const float* __restrict__ ln_bias,
    const float* __restrict__ W_e,       // [MSG][MSG]
    float*       __restrict__ msg)       // [N_NUC][MSG], pre-zeroed
{
    __shared__ float lds_o[256 * LDS_STR];
    __shared__ int   lds_r[256];

    const int t  = threadIdx.x;
    const int B0 = blockIdx.x * 256;     // first slot of this block

    // ---- phase 1: per-edge message (single-shot, straight-line) ----
    const int4 pk = edge_pack[B0 + t];
    const int e = pk.x, s = pk.y, r = pk.z;
    lds_r[t] = r;

    const float4* ee = reinterpret_cast<const float4*>(e_embed + (size_t)e * MSG_C);
    const float4* ps = reinterpret_cast<const float4*>(proj + (size_t)s * MSG_C);
    const float4* pq = reinterpret_cast<const float4*>(proj + (size_t)(N_NUC_C + r) * MSG_C);

    float ev[MSG_C], x[MSG_C];
    #pragma unroll
    for (int q = 0; q < 8; ++q) {
        const float4 v = ee[q];
        ev[4*q+0] = v.x; ev[4*q+1] = v.y; ev[4*q+2] = v.z; ev[4*q+3] = v.w;
    }
    #pragma unroll
    for (int q = 0; q < 8; ++q) {
        const float4 a = ps[q];
        const float4 b = pq[q];
        x[4*q+0] = a.x + b.x; x[4*q+1] = a.y + b.y;
        x[4*q+2] = a.z + b.z; x[4*q+3] = a.w + b.w;
    }

    // gate = e_embed[e] @ W_e (wave-uniform W_e -> scalar operands)
    float g[MSG_C];
    #pragma unroll
    for (int c = 0; c < MSG_C; ++c) g[c] = 0.0f;
    #pragma unroll
    for (int k = 0; k < MSG_C; ++k) {
        const float ek = ev[k];
        #pragma unroll
        for (int c = 0; c < MSG_C; ++c)
            g[c] = fmaf(ek, W_e[k * MSG_C + c], g[c]);
    }

    // LayerNorm + SiLU, write message straight to LDS
    float mu = 0.0f;
    #pragma unroll
    for (int c = 0; c < MSG_C; ++c) mu += x[c];
    mu *= (1.0f / MSG_C);
    float var = 0.0f;
    #pragma unroll
    for (int c = 0; c < MSG_C; ++c) { const float d = x[c] - mu; var = fmaf(d, d, var); }
    var *= (1.0f / MSG_C);
    const float rs = rsqrtf(var + 1e-6f);

    float* orow = &lds_o[t * LDS_STR];
    #pragma unroll
    for (int c = 0; c < MSG_C; ++c) {
        const float y = (x[c] - mu) * rs * ln_scale[c] + ln_bias[c];
        orow[c] = silu_f(y) * g[c];
    }

    __syncthreads();

    // ---- phase 2: segmented reduction over receivers in this block ----
    const int r0 = lds_r[0];
    const int r1 = lds_r[255];
    const int total = (r1 - r0 + 1) << 5;   // (#receivers) * 32 channels

    for (int p = t; p < total; p += 256) {
        const int n  = r0 + (p >> 5);
        const int ch = p & 31;
        int b  = offsets[n];
        int en = offsets[n + 1];
        const bool interior = (b >= B0) && (en <= B0 + 256);
        if (b < B0) b = B0;
        if (en > B0 + 256) en = B0 + 256;

        float sum = 0.0f;
        for (int q = b - B0; q < en - B0; ++q)
            sum += lds_o[q * LDS_STR + ch];

        float* dst = msg + (size_t)n * MSG_C + ch;
        if (interior)       *dst = sum;          // sole owner (incl. empty = 0)
        else if (en > b)    atomicAdd(dst, sum); // straddling segment part
    }
}

// ---------------------------------------------------------------------------
// Fallback (tiny ws): R1 atomic edge kernel
// ---------------------------------------------------------------------------
__global__ __launch_bounds__(256) void edge_kernel(
    const float* __restrict__ proj, const float* __restrict__ e_embed,
    const int* __restrict__ senders, const int* __restrict__ receivers,
    const float* __restrict__ ln_scale, const float* __restrict__ ln_bias,
    const float* __restrict__ W_e, float* __restrict__ msg)
{
    const int e = blockIdx.x * blockDim.x + threadIdx.x;
    if (e >= N_NN_C) return;
    const int s = senders[e];
    const int r = receivers[e];
    const float4* ps = reinterpret_cast<const float4*>(proj + (size_t)s * MSG_C);
    const float4* pq = reinterpret_cast<const float4*>(proj + (size_t)(N_NUC_C + r) * MSG_C);
    float x[MSG_C];
    #pragma unroll
    for (int q = 0; q < 8; ++q) {
        const float4 a = ps[q];
        const float4 b = pq[q];
        x[4*q+0] = a.x + b.x; x[4*q+1] = a.y + b.y;
        x[4*q+2] = a.z + b.z; x[4*q+3] = a.w + b.w;
    }
    float mu = 0.0f;
    #pragma unroll
    for (int c = 0; c < MSG_C; ++c) mu += x[c];
    mu *= (1.0f / MSG_C);
    float var = 0.0f;
    #pragma unroll
    for (int c = 0; c < MSG_C; ++c) { const float d = x[c] - mu; var = fmaf(d, d, var); }
    var *= (1.0f / MSG_C);
    const float rs = rsqrtf(var + 1e-6f);
    #pragma unroll
    for (int c = 0; c < MSG_C; ++c) {
        const float y = (x[c] - mu) * rs * ln_scale[c] + ln_bias[c];
        x[c] = silu_f(y);
    }
    float ev[MSG_C];
    const float4* ee = reinterpret_cast<const float4*>(e_embed + (size_t)e * MSG_C);
    #pragma unroll
    for (int q = 0; q < 8; ++q) {
        const float4 v = ee[q];
        ev[4*q+0] = v.x; ev[4*q+1] = v.y; ev[4*q+2] = v.z; ev[4*q+3] = v.w;
    }
    float g[MSG_C];
    #pragma unroll
    for (int c = 0; c < MSG_C; ++c) g[c] = 0.0f;
    #pragma unroll
    for (int k = 0; k < MSG_C; ++k) {
        const float ek = ev[k];
        #pragma unroll
        for (int c = 0; c < MSG_C; ++c) g[c] = fmaf(ek, W_e[k * MSG_C + c], g[c]);
    }
    float* mrow = msg + (size_t)r * MSG_C;
    #pragma unroll
    for (int c = 0; c < MSG_C; ++c) atomicAdd(mrow + c, x[c] * g[c]);
}

// ---------------------------------------------------------------------------
// Kernel C: out[n][j] = silu( (msg[n] . W_out[:,j]) * norm[n] )
// ---------------------------------------------------------------------------
__global__ __launch_bounds__(256) void out_kernel(
    const float* __restrict__ msg, const float* __restrict__ norm,
    const float* __restrict__ W_out, float* __restrict__ out)
{
    const int j     = threadIdx.x & (OUT_C - 1);
    const int local = threadIdx.x >> 7;

    float w[MSG_C];
    #pragma unroll
    for (int k = 0; k < MSG_C; ++k) w[k] = W_out[k * OUT_C + j];

    for (int n = blockIdx.x * 2 + local; n < N_NUC_C; n += gridDim.x * 2) {
        const float4* m4 = reinterpret_cast<const float4*>(msg + (size_t)n * MSG_C);
        float acc = 0.0f;
        #pragma unroll
        for (int q = 0; q < 8; ++q) {
            const float4 mv = m4[q];
            acc = fmaf(mv.x, w[4*q+0], acc);
            acc = fmaf(mv.y, w[4*q+1], acc);
            acc = fmaf(mv.z, w[4*q+2], acc);
            acc = fmaf(mv.w, w[4*q+3], acc);
        }
        acc *= norm[n];
        out[(size_t)n * OUT_C + j] = silu_f(acc);
    }
}

extern "C" void kernel_launch(void* const* d_in, const int* in_sizes, int n_in,
                              void* d_out, int out_size, void* d_ws, size_t ws_size,
                              hipStream_t stream) {
    const float* s_embed   = (const float*)d_in[0];
    const float* r_embed   = (const float*)d_in[1];
    const float* e_embed   = (const float*)d_in[2];
    const float* norm      = (const float*)d_in[3];
    const int*   senders   = (const int*)d_in[4];
    const int*   receivers = (const int*)d_in[5];
    const float* W_s       = (const float*)d_in[6];
    const float* b_s       = (const float*)d_in[7];
    const float* W_r       = (const float*)d_in[8];
    const float* b_r       = (const float*)d_in[9];
    const float* ln_scale  = (const float*)d_in[10];
    const float* ln_bias   = (const float*)d_in[11];
    const float* W_e       = (const float*)d_in[12];
    const float* W_out     = (const float*)d_in[13];
    float* out = (float*)d_out;

    char* ws = (char*)d_ws;
    size_t off = 0;
    auto alloc = [&](size_t bytes) { char* p = ws + off; off += (bytes + 255) & ~(size_t)255; return p; };

    float* proj      = (float*)alloc((size_t)2 * N_NUC_C * MSG_C * 4); // 25.6 MB
    float* msg       = (float*)alloc((size_t)N_NUC_C * MSG_C * 4);     // 12.8 MB
    const size_t off_min = off;                                        // 38.4 MB
    int*   cnt       = (int*)  alloc((size_t)N_NUC_C * 4);
    int*   excl      = (int*)  alloc((size_t)N_NUC_C * 4);
    int*   offsets   = (int*)  alloc((size_t)(N_NUC_C + 1) * 4);
    int*   cursor    = (int*)  alloc((size_t)N_NUC_C * 4);
    int*   blockTot  = (int*)  alloc(128 * 4);
    int*   blockOff  = (int*)  alloc(128 * 4);
    int4*  edge_pack = (int4*) alloc((size_t)N_NN_C * 16);             // 25.6 MB
    const size_t off_full = off;                                       // ~65.7 MB

    dim3 pgrid((N_NUC_C + 255) / 256, 4);
    proj_kernel<<<pgrid, 256, 0, stream>>>(s_embed, r_embed, W_s, b_s, W_r, b_r, proj);

    if (off_full <= ws_size) {
        // --- CSR + partition-local scatter + fused edge-compute/reduce ---
        hipMemsetAsync(cnt, 0, (size_t)N_NUC_C * 4, stream);
        hipMemsetAsync(msg, 0, (size_t)N_NUC_C * MSG_C * 4, stream);
        count_kernel<<<(N_NN_C + 255) / 256, 256, 0, stream>>>(receivers, cnt);
        scan1_kernel<<<NB1, 256, 0, stream>>>(cnt, excl, blockTot);
        scan2_kernel<<<1, 128, 0, stream>>>(blockTot, blockOff);
        scan3_kernel<<<(N_NUC_C + 255) / 256, 256, 0, stream>>>(excl, blockOff, offsets, cursor);
        scatter_pack8_kernel<<<NPART * SBLK, 256, 0, stream>>>(
            senders, receivers, cursor, edge_pack);
        fused_csr_kernel<<<N_NN_C / 256, 256, 0, stream>>>(
            proj, e_embed, edge_pack, offsets, ln_scale, ln_bias, W_e, msg);
    } else if (off_min <= ws_size) {
        // --- fallback: R1 atomic path ---
        hipMemsetAsync(msg, 0, (size_t)N_NUC_C * MSG_C * 4, stream);
        edge_kernel<<<(N_NN_C + 255) / 256, 256, 0, stream>>>(
            proj, e_embed, senders, receivers, ln_scale, ln_bias, W_e, msg);
    }

    out_kernel<<<2048, 256, 0, stream>>>(msg, norm, W_out, out);
}

// Round 7
// 364.835 us; speedup vs baseline: 2.3877x; 1.0282x over previous
//
#include <hip/hip_runtime.h>
#include <hip/hip_bf16.h>
#include <math.h>

#define N_NUC_C 100000
#define N_NN_C  1600000
#define EMB_C   128
#define MSG_C   32
#define OUT_C   128
#define NB1     98   // ceil(N_NUC / 1024) for the scan
#define NPART   8
#define R_PER_P (N_NUC_C / NPART)          // 12500 receivers per partition
#define SBLK    784                        // blocks per partition in scatter
#define STHREADS (SBLK * 256)              // 200704 threads per partition
#define LDS_USTR 17                        // uint row stride (16 packed + 1 pad, odd -> conflict-free)

__device__ __forceinline__ float silu_f(float y) {
    return y / (1.0f + __expf(-y));
}

// round-to-nearest-even f32->bf16, packed pair
__device__ __forceinline__ unsigned pack_bf16x2(float a, float b) {
    unsigned ua = __float_as_uint(a); ua += 0x7FFFu + ((ua >> 16) & 1u);
    unsigned ub = __float_as_uint(b); ub += 0x7FFFu + ((ub >> 16) & 1u);
    return (ua >> 16) | (ub & 0xFFFF0000u);
}

// ---------------------------------------------------------------------------
// Kernel A: node projections  proj[pr][n][c] = embed[n] @ W + b
// ---------------------------------------------------------------------------
__global__ __launch_bounds__(256) void proj_kernel(
    const float* __restrict__ s_embed, const float* __restrict__ r_embed,
    const float* __restrict__ W_s, const float* __restrict__ b_s,
    const float* __restrict__ W_r, const float* __restrict__ b_r,
    float* __restrict__ proj /* [2][N_NUC][MSG] */)
{
    const int n   = blockIdx.x * blockDim.x + threadIdx.x;
    const int sub = blockIdx.y;       // 0..3
    const int pr  = sub >> 1;
    const int c0  = (sub & 1) * 16;
    if (n >= N_NUC_C) return;

    const float* __restrict__ src = pr ? r_embed : s_embed;
    const float* __restrict__ W   = pr ? W_r : W_s;
    const float* __restrict__ b   = pr ? b_r : b_s;
    float* __restrict__ dst = proj + (size_t)pr * N_NUC_C * MSG_C;

    float acc[16];
    #pragma unroll
    for (int i = 0; i < 16; ++i) acc[i] = b[c0 + i];

    const float* row = src + (size_t)n * EMB_C;
    #pragma unroll 4
    for (int k = 0; k < EMB_C; k += 4) {
        const float4 rv = *reinterpret_cast<const float4*>(row + k);
        #pragma unroll
        for (int i = 0; i < 16; ++i) {
            acc[i] = fmaf(rv.x, W[(k + 0) * MSG_C + c0 + i], acc[i]);
            acc[i] = fmaf(rv.y, W[(k + 1) * MSG_C + c0 + i], acc[i]);
            acc[i] = fmaf(rv.z, W[(k + 2) * MSG_C + c0 + i], acc[i]);
            acc[i] = fmaf(rv.w, W[(k + 3) * MSG_C + c0 + i], acc[i]);
        }
    }

    float4* d = reinterpret_cast<float4*>(dst + (size_t)n * MSG_C + c0);
    d[0] = make_float4(acc[0],  acc[1],  acc[2],  acc[3]);
    d[1] = make_float4(acc[4],  acc[5],  acc[6],  acc[7]);
    d[2] = make_float4(acc[8],  acc[9],  acc[10], acc[11]);
    d[3] = make_float4(acc[12], acc[13], acc[14], acc[15]);
}

// ---------------------------------------------------------------------------
// CSR build: single atomic pass — rank[e] = running index within receiver
// ---------------------------------------------------------------------------
__global__ __launch_bounds__(256) void rank_kernel(
    const int* __restrict__ receivers, int* __restrict__ cnt,
    int* __restrict__ rank)
{
    const int e = blockIdx.x * blockDim.x + threadIdx.x;
    if (e >= N_NN_C) return;
    rank[e] = atomicAdd(&cnt[receivers[e]], 1);
}

// Exclusive scan of cnt[N_NUC] -> offsets. Three tiny kernels.
__global__ __launch_bounds__(256) void scan1_kernel(
    const int* __restrict__ cnt, int* __restrict__ excl, int* __restrict__ blockTot)
{
    __shared__ int waveTot[4];
    const int t = threadIdx.x, b = blockIdx.x;
    const int lane = t & 63, wid = t >> 6;
    const int base = b * 1024 + t * 4;

    int d0 = (base + 0 < N_NUC_C) ? cnt[base + 0] : 0;
    int d1 = (base + 1 < N_NUC_C) ? cnt[base + 1] : 0;
    int d2 = (base + 2 < N_NUC_C) ? cnt[base + 2] : 0;
    int d3 = (base + 3 < N_NUC_C) ? cnt[base + 3] : 0;
    const int s = d0 + d1 + d2 + d3;

    int incl = s;
    #pragma unroll
    for (int off = 1; off < 64; off <<= 1) {
        int v = __shfl_up(incl, off);
        if (lane >= off) incl += v;
    }
    const int wexcl = incl - s;
    if (lane == 63) waveTot[wid] = incl;
    __syncthreads();
    int wbase = 0;
    for (int w = 0; w < wid; ++w) wbase += waveTot[w];
    const int e0 = wbase + wexcl;

    if (base + 0 < N_NUC_C) excl[base + 0] = e0;
    if (base + 1 < N_NUC_C) excl[base + 1] = e0 + d0;
    if (base + 2 < N_NUC_C) excl[base + 2] = e0 + d0 + d1;
    if (base + 3 < N_NUC_C) excl[base + 3] = e0 + d0 + d1 + d2;
    if (t == 255) blockTot[b] = wbase + incl;
}

__global__ __launch_bounds__(128) void scan2_kernel(
    const int* __restrict__ blockTot, int* __restrict__ blockOff)
{
    __shared__ int sh[128];
    const int t = threadIdx.x;
    const int v = (t < NB1) ? blockTot[t] : 0;
    sh[t] = v;
    __syncthreads();
    #pragma unroll
    for (int off = 1; off < 128; off <<= 1) {
        int x = 0;
        if (t >= off) x = sh[t - off];
        __syncthreads();
        sh[t] += x;
        __syncthreads();
    }
    if (t < NB1) blockOff[t] = sh[t] - v;
}

__global__ __launch_bounds__(256) void scan3_kernel(
    const int* __restrict__ excl, const int* __restrict__ blockOff,
    int* __restrict__ offsets)
{
    const int n = blockIdx.x * blockDim.x + threadIdx.x;
    if (n < N_NUC_C) offsets[n] = excl[n] + blockOff[n >> 10];
    if (n == 0) offsets[N_NUC_C] = N_NN_C;
}

// ---------------------------------------------------------------------------
// Partition-local ATOMIC-FREE scatter: 8 receiver ranges; blocks with
// blockIdx%8==p scan all edges (coalesced) and scatter only those with r in
// range p to dst = offsets[r] + rank[e] (unique by construction). Pack lines
// are written by one partition's clustered blocks -> L2 write coalescing.
// ---------------------------------------------------------------------------
__global__ __launch_bounds__(256) void scatter_pack8_kernel(
    const int* __restrict__ senders, const int* __restrict__ receivers,
    const int* __restrict__ rank, const int* __restrict__ offsets,
    int4* __restrict__ edge_pack)
{
    const int p    = blockIdx.x & 7;
    const int blk  = blockIdx.x >> 3;                 // 0..SBLK-1
    const int base = blk * 256 + threadIdx.x;         // 0..STHREADS-1
    const int rlo  = p * R_PER_P;
    const int rhi  = rlo + R_PER_P;

    #pragma unroll
    for (int k = 0; k < 8; ++k) {
        const int e = base + k * STHREADS;
        if (e < N_NN_C) {
            const int r = receivers[e];
            if (r >= rlo && r < rhi) {
                const int dst = offsets[r] + rank[e];
                edge_pack[dst] = make_int4(e, senders[e], r, 0);
            }
        }
    }
}

// ---------------------------------------------------------------------------
// Fused CSR edge compute + in-block segmented reduction.
// Block = 256 consecutive CSR slots. Thread = one slot, single-shot math.
// Messages staged in LDS as packed bf16x2 (uint[256][17], odd stride ->
// conflict-free; 18.4 KB -> ~7 blocks/CU vs 4 with f32). Reduction in f32.
// Interior segments plain-store, straddling segments atomicAdd.
// ---------------------------------------------------------------------------
__global__ __launch_bounds__(256) void fused_csr_kernel(
    const float* __restrict__ proj,      // [2][N_NUC][MSG]
    const float* __restrict__ e_embed,   // [N_NN][MSG]
    const int4*  __restrict__ edge_pack, // [N_NN] (e, s, r, 0) CSR order
    const int*   __restrict__ offsets,   // [N_NUC+1]
    const float* __restrict__ ln_scale,
    const float* __restrict__ ln_bias,
    const float* __restrict__ W_e,       // [MSG][MSG]
    float*       __restrict__ msg)       // [N_NUC][MSG], pre-zeroed
{
    __shared__ unsigned lds_u[256 * LDS_USTR];
    __shared__ int      lds_r[256];

    const int t  = threadIdx.x;
    const int B0 = blockIdx.x * 256;     // first slot of this block

    // ---- phase 1: per-edge message (single-shot, straight-line) ----
    const int4 pk = edge_pack[B0 + t];
    const int e = pk.x, s = pk.y, r = pk.z;
    lds_r[t] = r;

    const float4* ee = reinterpret_cast<const float4*>(e_embed + (size_t)e * MSG_C);
    const float4* ps = reinterpret_cast<const float4*>(proj + (size_t)s * MSG_C);
    const float4* pq = reinterpret_cast<const float4*>(proj + (size_t)(N_NUC_C + r) * MSG_C);

    float ev[MSG_C], x[MSG_C];
    #pragma unroll
    for (int q = 0; q < 8; ++q) {
        const float4 v = ee[q];
        ev[4*q+0] = v.x; ev[4*q+1] = v.y; ev[4*q+2] = v.z; ev[4*q+3] = v.w;
    }
    #pragma unroll
    for (int q = 0; q < 8; ++q) {
        const float4 a = ps[q];
        const float4 b = pq[q];
        x[4*q+0] = a.x + b.x; x[4*q+1] = a.y + b.y;
        x[4*q+2] = a.z + b.z; x[4*q+3] = a.w + b.w;
    }

    // gate = e_embed[e] @ W_e (wave-uniform W_e -> scalar operands)
    float g[MSG_C];
    #pragma unroll
    for (int c = 0; c < MSG_C; ++c) g[c] = 0.0f;
    #pragma unroll
    for (int k = 0; k < MSG_C; ++k) {
        const float ek = ev[k];
        #pragma unroll
        for (int c = 0; c < MSG_C; ++c)
            g[c] = fmaf(ek, W_e[k * MSG_C + c], g[c]);
    }

    // LayerNorm + SiLU, write packed bf16 message to LDS
    float mu = 0.0f;
    #pragma unroll
    for (int c = 0; c < MSG_C; ++c) mu += x[c];
    mu *= (1.0f / MSG_C);
    float var = 0.0f;
    #pragma unroll
    for (int c = 0; c < MSG_C; ++c) { const float d = x[c] - mu; var = fmaf(d, d, var); }
    var *= (1.0f / MSG_C);
    const float rs = rsqrtf(var + 1e-6f);

    unsigned* orow = &lds_u[t * LDS_USTR];
    #pragma unroll
    for (int i = 0; i < 16; ++i) {
        const int c0_ = 2*i, c1_ = 2*i + 1;
        const float y0 = (x[c0_] - mu) * rs * ln_scale[c0_] + ln_bias[c0_];
        const float y1 = (x[c1_] - mu) * rs * ln_scale[c1_] + ln_bias[c1_];
        orow[i] = pack_bf16x2(silu_f(y0) * g[c0_], silu_f(y1) * g[c1_]);
    }

    __syncthreads();

    // ---- phase 2: segmented reduction over receivers in this block ----
    const int r0 = lds_r[0];
    const int r1 = lds_r[255];
    const int total = (r1 - r0 + 1) << 5;   // (#receivers) * 32 channels

    for (int p = t; p < total; p += 256) {
        const int n  = r0 + (p >> 5);
        const int ch = p & 31;
        int b  = offsets[n];
        int en = offsets[n + 1];
        const bool interior = (b >= B0) && (en <= B0 + 256);
        if (b < B0) b = B0;
        if (en > B0 + 256) en = B0 + 256;

        const int dw  = ch >> 1;
        const bool hi = (ch & 1);
        float sum = 0.0f;
        for (int q = b - B0; q < en - B0; ++q) {
            const unsigned u = lds_u[q * LDS_USTR + dw];
            sum += __uint_as_float(hi ? (u & 0xFFFF0000u) : (u << 16));
        }

        float* dst = msg + (size_t)n * MSG_C + ch;
        if (interior)       *dst = sum;          // sole owner (incl. empty = 0)
        else if (en > b)    atomicAdd(dst, sum); // straddling segment part
    }
}

// ---------------------------------------------------------------------------
// Fallback (tiny ws): R1 atomic edge kernel
// ---------------------------------------------------------------------------
__global__ __launch_bounds__(256) void edge_kernel(
    const float* __restrict__ proj, const float* __restrict__ e_embed,
    const int* __restrict__ senders, const int* __restrict__ receivers,
    const float* __restrict__ ln_scale, const float* __restrict__ ln_bias,
    const float* __restrict__ W_e, float* __restrict__ msg)
{
    const int e = blockIdx.x * blockDim.x + threadIdx.x;
    if (e >= N_NN_C) return;
    const int s = senders[e];
    const int r = receivers[e];
    const float4* ps = reinterpret_cast<const float4*>(proj + (size_t)s * MSG_C);
    const float4* pq = reinterpret_cast<const float4*>(proj + (size_t)(N_NUC_C + r) * MSG_C);
    float x[MSG_C];
    #pragma unroll
    for (int q = 0; q < 8; ++q) {
        const float4 a = ps[q];
        const float4 b = pq[q];
        x[4*q+0] = a.x + b.x; x[4*q+1] = a.y + b.y;
        x[4*q+2] = a.z + b.z; x[4*q+3] = a.w + b.w;
    }
    float mu = 0.0f;
    #pragma unroll
    for (int c = 0; c < MSG_C; ++c) mu += x[c];
    mu *= (1.0f / MSG_C);
    float var = 0.0f;
    #pragma unroll
    for (int c = 0; c < MSG_C; ++c) { const float d = x[c] - mu; var = fmaf(d, d, var); }
    var *= (1.0f / MSG_C);
    const float rs = rsqrtf(var + 1e-6f);
    #pragma unroll
    for (int c = 0; c < MSG_C; ++c) {
        const float y = (x[c] - mu) * rs * ln_scale[c] + ln_bias[c];
        x[c] = silu_f(y);
    }
    float ev[MSG_C];
    const float4* ee = reinterpret_cast<const float4*>(e_embed + (size_t)e * MSG_C);
    #pragma unroll
    for (int q = 0; q < 8; ++q) {
        const float4 v = ee[q];
        ev[4*q+0] = v.x; ev[4*q+1] = v.y; ev[4*q+2] = v.z; ev[4*q+3] = v.w;
    }
    float g[MSG_C];
    #pragma unroll
    for (int c = 0; c < MSG_C; ++c) g[c] = 0.0f;
    #pragma unroll
    for (int k = 0; k < MSG_C; ++k) {
        const float ek = ev[k];
        #pragma unroll
        for (int c = 0; c < MSG_C; ++c) g[c] = fmaf(ek, W_e[k * MSG_C + c], g[c]);
    }
    float* mrow = msg + (size_t)r * MSG_C;
    #pragma unroll
    for (int c = 0; c < MSG_C; ++c) atomicAdd(mrow + c, x[c] * g[c]);
}

// ---------------------------------------------------------------------------
// Kernel C: out[n][j] = silu( (msg[n] . W_out[:,j]) * norm[n] )
// ---------------------------------------------------------------------------
__global__ __launch_bounds__(256) void out_kernel(
    const float* __restrict__ msg, const float* __restrict__ norm,
    const float* __restrict__ W_out, float* __restrict__ out)
{
    const int j     = threadIdx.x & (OUT_C - 1);
    const int local = threadIdx.x >> 7;

    float w[MSG_C];
    #pragma unroll
    for (int k = 0; k < MSG_C; ++k) w[k] = W_out[k * OUT_C + j];

    for (int n = blockIdx.x * 2 + local; n < N_NUC_C; n += gridDim.x * 2) {
        const float4* m4 = reinterpret_cast<const float4*>(msg + (size_t)n * MSG_C);
        float acc = 0.0f;
        #pragma unroll
        for (int q = 0; q < 8; ++q) {
            const float4 mv = m4[q];
            acc = fmaf(mv.x, w[4*q+0], acc);
            acc = fmaf(mv.y, w[4*q+1], acc);
            acc = fmaf(mv.z, w[4*q+2], acc);
            acc = fmaf(mv.w, w[4*q+3], acc);
        }
        acc *= norm[n];
        out[(size_t)n * OUT_C + j] = silu_f(acc);
    }
}

extern "C" void kernel_launch(void* const* d_in, const int* in_sizes, int n_in,
                              void* d_out, int out_size, void* d_ws, size_t ws_size,
                              hipStream_t stream) {
    const float* s_embed   = (const float*)d_in[0];
    const float* r_embed   = (const float*)d_in[1];
    const float* e_embed   = (const float*)d_in[2];
    const float* norm      = (const float*)d_in[3];
    const int*   senders   = (const int*)d_in[4];
    const int*   receivers = (const int*)d_in[5];
    const float* W_s       = (const float*)d_in[6];
    const float* b_s       = (const float*)d_in[7];
    const float* W_r       = (const float*)d_in[8];
    const float* b_r       = (const float*)d_in[9];
    const float* ln_scale  = (const float*)d_in[10];
    const float* ln_bias   = (const float*)d_in[11];
    const float* W_e       = (const float*)d_in[12];
    const float* W_out     = (const float*)d_in[13];
    float* out = (float*)d_out;

    char* ws = (char*)d_ws;
    size_t off = 0;
    auto alloc = [&](size_t bytes) { char* p = ws + off; off += (bytes + 255) & ~(size_t)255; return p; };

    float* proj      = (float*)alloc((size_t)2 * N_NUC_C * MSG_C * 4); // 25.6 MB
    float* msg       = (float*)alloc((size_t)N_NUC_C * MSG_C * 4);     // 12.8 MB
    const size_t off_min = off;                                        // 38.4 MB
    int*   cnt       = (int*)  alloc((size_t)N_NUC_C * 4);
    int*   excl      = (int*)  alloc((size_t)N_NUC_C * 4);
    int*   offsets   = (int*)  alloc((size_t)(N_NUC_C + 1) * 4);
    int*   blockTot  = (int*)  alloc(128 * 4);
    int*   blockOff  = (int*)  alloc(128 * 4);
    int*   rank      = (int*)  alloc((size_t)N_NN_C * 4);              // 6.4 MB
    int4*  edge_pack = (int4*) alloc((size_t)N_NN_C * 16);             // 25.6 MB
    const size_t off_full = off;                                       // ~72 MB

    dim3 pgrid((N_NUC_C + 255) / 256, 4);
    proj_kernel<<<pgrid, 256, 0, stream>>>(s_embed, r_embed, W_s, b_s, W_r, b_r, proj);

    if (off_full <= ws_size) {
        // --- CSR (1 atomic pass) + partition-local atomic-free scatter +
        //     fused edge-compute/in-block-reduce (bf16 LDS staging) ---
        hipMemsetAsync(cnt, 0, (size_t)N_NUC_C * 4, stream);
        hipMemsetAsync(msg, 0, (size_t)N_NUC_C * MSG_C * 4, stream);
        rank_kernel<<<(N_NN_C + 255) / 256, 256, 0, stream>>>(receivers, cnt, rank);
        scan1_kernel<<<NB1, 256, 0, stream>>>(cnt, excl, blockTot);
        scan2_kernel<<<1, 128, 0, stream>>>(blockTot, blockOff);
        scan3_kernel<<<(N_NUC_C + 255) / 256, 256, 0, stream>>>(excl, blockOff, offsets);
        scatter_pack8_kernel<<<NPART * SBLK, 256, 0, stream>>>(
            senders, receivers, rank, offsets, edge_pack);
        fused_csr_kernel<<<N_NN_C / 256, 256, 0, stream>>>(
            proj, e_embed, edge_pack, offsets, ln_scale, ln_bias, W_e, msg);
    } else if (off_min <= ws_size) {
        // --- fallback: R1 atomic path ---
        hipMemsetAsync(msg, 0, (size_t)N_NUC_C * MSG_C * 4, stream);
        edge_kernel<<<(N_NN_C + 255) / 256, 256, 0, stream>>>(
            proj, e_embed, senders, receivers, ln_scale, ln_bias, W_e, msg);
    }

    out_kernel<<<2048, 256, 0, stream>>>(msg, norm, W_out, out);
}